// Round 1
// baseline (810.989 us; speedup 1.0000x reference)
//
#include <hip/hip_runtime.h>

#define T_ 30
#define H_ 41
#define WD_ 2048
#define NSEC 9
#define KH 6
#define KW 40
#define FM 50
#define WP 502            // pooled width
#define THRESH 23.0f
#define XT 296            // LDS x-tile cols (256 + 39 halo, rounded to 296)
#define POOLED_SIZE (NSEC * T_ * FM * WP)   // 6,777,000

// ---------------- Kernel A: conv + threshold + 4x4 max-pool ----------------
// block: 256 = 64 pooled-cols x 4 feature maps
// grid : 9 sec * 30 t * 13 fm-groups * 8 w-tiles = 28080
__global__ __launch_bounds__(256) void conv_pool_kernel(
    const float* __restrict__ x, const float* __restrict__ Wg,
    float* __restrict__ out)
{
    __shared__ float lx[9 * XT];      // 9 rows x 296 cols
    __shared__ float lw[4 * 240];     // 4 fms x (6*40)

    const int b   = blockIdx.x;
    const int wt  = b & 7;            // 8 w-tiles
    const int fmg = (b >> 3) % 13;    // 13 fm-groups of 4
    const int tt  = (b / 104) % T_;
    const int sec = b / 3120;

    const int tid     = threadIdx.x;
    const int colbase = wt * 256;     // pot-col base of this tile
    const int rowbase = 4 * sec;

    // stage x tile: 9 rows x 74 float4
    for (int i = tid; i < 9 * 74; i += 256) {
        const int row  = i / 74;
        const int c4   = i % 74;
        const int gcol = colbase + 4 * c4;
        float4 v;
        if (gcol + 3 < WD_) {
            v = *reinterpret_cast<const float4*>(
                x + (size_t)(tt * H_ + rowbase + row) * WD_ + gcol);
        } else {
            v.x = v.y = v.z = v.w = 0.f;   // tiles are 16B-aligned vs the 2048 edge
        }
        *reinterpret_cast<float4*>(&lx[row * XT + 4 * c4]) = v;
    }

    // stage W for 4 fms: 4 x 60 float4
    const int fm0 = fmg * 4;
    for (int i = tid; i < 4 * 60; i += 256) {
        const int fl = i / 60;
        const int q  = i % 60;
        const int fm = fm0 + fl;
        float4 v;
        if (fm < FM) {
            v = *reinterpret_cast<const float4*>(
                Wg + (size_t)(sec * FM + fm) * 240 + 4 * q);
        } else {
            v.x = v.y = v.z = v.w = 0.f;
        }
        *reinterpret_cast<float4*>(&lw[fl * 240 + 4 * q]) = v;
    }
    __syncthreads();

    const int wpl = tid & 63;    // pooled col within tile (wave-contiguous)
    const int fl  = tid >> 6;    // fm within group (wave-uniform)

    float acc[4][4];             // [h_out j][pot col wi]
#pragma unroll
    for (int j = 0; j < 4; ++j)
#pragma unroll
        for (int wi = 0; wi < 4; ++wi) acc[j][wi] = 0.f;

    const float* wbase = &lw[fl * 240];

#pragma unroll
    for (int a = 0; a < 9; ++a) {                 // absolute section row
        const float* xr = &lx[a * XT + 4 * wpl];
        float xv[8];
        {
            float4 c0 = *reinterpret_cast<const float4*>(xr);
            xv[0] = c0.x; xv[1] = c0.y; xv[2] = c0.z; xv[3] = c0.w;
        }
#pragma unroll 1
        for (int cq = 0; cq < 10; ++cq) {         // kernel cols in chunks of 4
            float4 nx = *reinterpret_cast<const float4*>(xr + 4 * cq + 4);
            xv[4] = nx.x; xv[5] = nx.y; xv[6] = nx.z; xv[7] = nx.w;
#pragma unroll
            for (int j = 0; j < 4; ++j) {
                if (j > a || j < a - 5) continue; // compile-time (a,j unrolled)
                const int r = a - j;
                float4 w4 = *reinterpret_cast<const float4*>(wbase + r * 40 + 4 * cq);
                float wa[4] = {w4.x, w4.y, w4.z, w4.w};
#pragma unroll
                for (int cc = 0; cc < 4; ++cc)
#pragma unroll
                    for (int wi = 0; wi < 4; ++wi)
                        acc[j][wi] = fmaf(xv[wi + cc], wa[cc], acc[j][wi]);
            }
            xv[0] = xv[4]; xv[1] = xv[5]; xv[2] = xv[6]; xv[3] = xv[7];
        }
    }

    bool any = false;
#pragma unroll
    for (int j = 0; j < 4; ++j)
#pragma unroll
        for (int wi = 0; wi < 4; ++wi) any = any || (acc[j][wi] > THRESH);

    const int wp = colbase / 4 * 1 + wpl + wt * 0 + (wt * 64 - colbase / 4) + colbase / 4; // = wt*64 + wpl
    const int wp_real = wt * 64 + wpl;
    const int fm = fm0 + fl;
    (void)wp;
    if (wp_real < WP && fm < FM) {
        out[((size_t)(sec * T_ + tt) * FM + fm) * WP + wp_real] = any ? 1.0f : 0.0f;
    }
}

// ---------------- Kernel B: init workspace ----------------
__global__ void init_kernel(int* __restrict__ ws)
{
    if (threadIdx.x < NSEC) ws[threadIdx.x] = 0x7fffffff;
}

// ---------------- Kernel C: first-spike scan + argmin reduce ----------------
// grid: 9 sections * 99 blocks (blocks never cross a section)
__global__ __launch_bounds__(256) void scan_kernel(
    const float* __restrict__ pooled, int* __restrict__ ws)
{
    __shared__ int sk[256];
    const int sec = blockIdx.x / 99;
    const int bi  = blockIdx.x % 99;
    const int e   = bi * 256 + threadIdx.x;   // flat (fm*WP + wp) within section
    int key = 0x7fffffff;
    if (e < FM * WP) {
        const int fm = e / WP;
        const int wp = e % WP;
        const size_t base = ((size_t)(sec * T_) * FM + fm) * WP + wp;
        const size_t tstride = (size_t)FM * WP;
#pragma unroll 1
        for (int t = 0; t < T_; ++t) {
            if (pooled[base + t * tstride] > 0.f) { key = (t << 15) | e; break; }
        }
    }
    sk[threadIdx.x] = key;
    __syncthreads();
    for (int s = 128; s > 0; s >>= 1) {
        if (threadIdx.x < s) sk[threadIdx.x] = min(sk[threadIdx.x], sk[threadIdx.x + s]);
        __syncthreads();
    }
    if (threadIdx.x == 0) atomicMin(&ws[sec], sk[0]);
}

// ---------------- Kernel D: finalize winners ----------------
__global__ void finalize_kernel(const int* __restrict__ ws, float* __restrict__ out)
{
    const int i = threadIdx.x;
    if (i < NSEC) {
        const int key = ws[i];
        float feat;
        if (key == 0x7fffffff) feat = -1.0f;
        else                   feat = (float)((key & 32767) / WP);
        out[POOLED_SIZE + i] = feat;
    }
}

extern "C" void kernel_launch(void* const* d_in, const int* in_sizes, int n_in,
                              void* d_out, int out_size, void* d_ws, size_t ws_size,
                              hipStream_t stream) {
    const float* x  = (const float*)d_in[0];
    const float* Wg = (const float*)d_in[1];
    float* out = (float*)d_out;
    int*   ws  = (int*)d_ws;

    hipLaunchKernelGGL(init_kernel, dim3(1), dim3(64), 0, stream, ws);
    hipLaunchKernelGGL(conv_pool_kernel, dim3(28080), dim3(256), 0, stream, x, Wg, out);
    hipLaunchKernelGGL(scan_kernel, dim3(NSEC * 99), dim3(256), 0, stream, out, ws);
    hipLaunchKernelGGL(finalize_kernel, dim3(1), dim3(16), 0, stream, ws, out);
}

// Round 2
// 807.263 us; speedup vs baseline: 1.0046x; 1.0046x over previous
//
#include <hip/hip_runtime.h>

#define T_ 30
#define H_ 41
#define WD_ 2048
#define NSEC 9
#define KH 6
#define KW 40
#define FM 50
#define WP 502            // pooled width
#define THRESH 23.0f
#define XT 296            // LDS x-tile cols (256 + 39 halo, rounded to 296)
#define POOLED_SIZE (NSEC * T_ * FM * WP)   // 6,777,000

// ---------------- Kernel A: conv + threshold + 4x4 max-pool ----------------
// block: 256 = 64 pooled-cols x 4 feature maps (fm wave-uniform -> scalar W)
// grid : 9 sec * 30 t * 13 fm-groups * 8 w-tiles = 28080
// R2: W via scalar loads from global (was 240 ds_read_b128/thread = 71% of
//     LDS traffic). x via 9-row register sliding window: 108 ds_read/thread.
__global__ __launch_bounds__(256, 4) void conv_pool_kernel(
    const float* __restrict__ x, const float* __restrict__ Wg,
    float* __restrict__ out)
{
    __shared__ float lx[9 * XT];      // 9 rows x 296 cols = 10.4 KB

    const int b   = blockIdx.x;
    const int wt  = b & 7;            // 8 w-tiles
    const int fmg = (b >> 3) % 13;    // 13 fm-groups of 4
    const int tt  = (b / 104) % T_;
    const int sec = b / 3120;

    const int tid     = threadIdx.x;
    const int colbase = wt * 256;     // pot-col base of this tile
    const int rowbase = 4 * sec;

    // stage x tile: 9 rows x 74 float4
    for (int i = tid; i < 9 * 74; i += 256) {
        const int row  = i / 74;
        const int c4   = i % 74;
        const int gcol = colbase + 4 * c4;
        float4 v;
        if (gcol + 3 < WD_) {
            v = *reinterpret_cast<const float4*>(
                x + (size_t)(tt * H_ + rowbase + row) * WD_ + gcol);
        } else {
            v.x = v.y = v.z = v.w = 0.f;
        }
        *reinterpret_cast<float4*>(&lx[row * XT + 4 * c4]) = v;
    }
    __syncthreads();

    const int wpl = tid & 63;    // pooled col within tile (wave-contiguous)
    const int fl  = tid >> 6;    // fm within group (wave-uniform!)
    const int fm0 = fmg * 4;
    const int fm  = fm0 + fl;

    // force scalar (SGPR) weight address: fm is uniform across the wave
    int fm_u = __builtin_amdgcn_readfirstlane(fm);
    fm_u = fm_u < FM - 1 ? fm_u : FM - 1;          // clamp OOB fm (50,51) - discarded at store
    const float* __restrict__ wrow = Wg + (size_t)(sec * FM + fm_u) * 240;

    float acc[4][4];             // [pot row j][pot col wi]
#pragma unroll
    for (int j = 0; j < 4; ++j)
#pragma unroll
        for (int wi = 0; wi < 4; ++wi) acc[j][wi] = 0.f;

    // register sliding window: xv[a][0..7] = x[row a][4*wpl + 4*cq .. +7]
    float xv[9][8];
#pragma unroll
    for (int a = 0; a < 9; ++a) {
        float4 c0 = *reinterpret_cast<const float4*>(&lx[a * XT + 4 * wpl]);
        xv[a][0] = c0.x; xv[a][1] = c0.y; xv[a][2] = c0.z; xv[a][3] = c0.w;
    }

#pragma unroll 1
    for (int cq = 0; cq < 10; ++cq) {             // kernel cols in chunks of 4
#pragma unroll
        for (int a = 0; a < 9; ++a) {
            float4 nx = *reinterpret_cast<const float4*>(
                &lx[a * XT + 4 * wpl + 4 * cq + 4]);
            xv[a][4] = nx.x; xv[a][5] = nx.y; xv[a][6] = nx.z; xv[a][7] = nx.w;
        }
#pragma unroll
        for (int r = 0; r < 6; ++r) {             // weight row
            const float* wr = wrow + r * 40 + 4 * cq;
            const float w0 = wr[0], w1 = wr[1], w2 = wr[2], w3 = wr[3];
#pragma unroll
            for (int j = 0; j < 4; ++j) {         // pot row; x row a = r + j
                const int a = r + j;
#pragma unroll
                for (int wi = 0; wi < 4; ++wi) {
                    acc[j][wi] = fmaf(xv[a][0 + wi], w0, acc[j][wi]);
                    acc[j][wi] = fmaf(xv[a][1 + wi], w1, acc[j][wi]);
                    acc[j][wi] = fmaf(xv[a][2 + wi], w2, acc[j][wi]);
                    acc[j][wi] = fmaf(xv[a][3 + wi], w3, acc[j][wi]);
                }
            }
        }
#pragma unroll
        for (int a = 0; a < 9; ++a) {
            xv[a][0] = xv[a][4]; xv[a][1] = xv[a][5];
            xv[a][2] = xv[a][6]; xv[a][3] = xv[a][7];
        }
    }

    bool any = false;
#pragma unroll
    for (int j = 0; j < 4; ++j)
#pragma unroll
        for (int wi = 0; wi < 4; ++wi) any = any || (acc[j][wi] > THRESH);

    const int wp_real = wt * 64 + wpl;
    if (wp_real < WP && fm < FM) {
        out[((size_t)(sec * T_ + tt) * FM + fm) * WP + wp_real] = any ? 1.0f : 0.0f;
    }
}

// ---------------- Kernel B: init workspace ----------------
__global__ void init_kernel(int* __restrict__ ws)
{
    if (threadIdx.x < NSEC) ws[threadIdx.x] = 0x7fffffff;
}

// ---------------- Kernel C: first-spike scan + argmin reduce ----------------
// grid: 9 sections * 99 blocks (blocks never cross a section)
__global__ __launch_bounds__(256) void scan_kernel(
    const float* __restrict__ pooled, int* __restrict__ ws)
{
    __shared__ int sk[256];
    const int sec = blockIdx.x / 99;
    const int bi  = blockIdx.x % 99;
    const int e   = bi * 256 + threadIdx.x;   // flat (fm*WP + wp) within section
    int key = 0x7fffffff;
    if (e < FM * WP) {
        const int fm = e / WP;
        const int wp = e % WP;
        const size_t base = ((size_t)(sec * T_) * FM + fm) * WP + wp;
        const size_t tstride = (size_t)FM * WP;
#pragma unroll 1
        for (int t = 0; t < T_; ++t) {
            if (pooled[base + t * tstride] > 0.f) { key = (t << 15) | e; break; }
        }
    }
    sk[threadIdx.x] = key;
    __syncthreads();
    for (int s = 128; s > 0; s >>= 1) {
        if (threadIdx.x < s) sk[threadIdx.x] = min(sk[threadIdx.x], sk[threadIdx.x + s]);
        __syncthreads();
    }
    if (threadIdx.x == 0) atomicMin(&ws[sec], sk[0]);
}

// ---------------- Kernel D: finalize winners ----------------
__global__ void finalize_kernel(const int* __restrict__ ws, float* __restrict__ out)
{
    const int i = threadIdx.x;
    if (i < NSEC) {
        const int key = ws[i];
        float feat;
        if (key == 0x7fffffff) feat = -1.0f;
        else                   feat = (float)((key & 32767) / WP);
        out[POOLED_SIZE + i] = feat;
    }
}

extern "C" void kernel_launch(void* const* d_in, const int* in_sizes, int n_in,
                              void* d_out, int out_size, void* d_ws, size_t ws_size,
                              hipStream_t stream) {
    const float* x  = (const float*)d_in[0];
    const float* Wg = (const float*)d_in[1];
    float* out = (float*)d_out;
    int*   ws  = (int*)d_ws;

    hipLaunchKernelGGL(init_kernel, dim3(1), dim3(64), 0, stream, ws);
    hipLaunchKernelGGL(conv_pool_kernel, dim3(28080), dim3(256), 0, stream, x, Wg, out);
    hipLaunchKernelGGL(scan_kernel, dim3(NSEC * 99), dim3(256), 0, stream, out, ws);
    hipLaunchKernelGGL(finalize_kernel, dim3(1), dim3(16), 0, stream, ws, out);
}

// Round 3
// 664.483 us; speedup vs baseline: 1.2205x; 1.2149x over previous
//
#include <hip/hip_runtime.h>

#define T_ 30
#define H_ 41
#define WD_ 2048
#define NSEC 9
#define KH 6
#define KW 40
#define FM 50
#define WP 502            // pooled width
#define THRESH 23.0f
#define XT 296            // LDS x-tile cols (256 + 39 halo, rounded to 296)
#define POOLED_SIZE (NSEC * T_ * FM * WP)   // 6,777,000

// ---------------- Kernel A: conv + threshold + 4x4 max-pool ----------------
// block: 256 = 64 pooled-cols x 4 feature maps (fm wave-uniform -> scalar W)
// grid : 9 sec * 30 t * 13 fm-groups * 8 w-tiles = 28080
// R3: a-outer / cq-inner so only ONE row's 8-float window is live (~40 VGPR;
//     R2's 9-row window at launch_bounds(256,4) scalarized into conflicted
//     ds_read_b32 — 1.4e8 bank-conflict cycles). W stays on the scalar path.
__global__ __launch_bounds__(256) void conv_pool_kernel(
    const float* __restrict__ x, const float* __restrict__ Wg,
    float* __restrict__ out)
{
    __shared__ float lx[9 * XT];      // 9 rows x 296 cols = 10.4 KB

    const int b   = blockIdx.x;
    const int wt  = b & 7;            // 8 w-tiles
    const int fmg = (b >> 3) % 13;    // 13 fm-groups of 4
    const int tt  = (b / 104) % T_;
    const int sec = b / 3120;

    const int tid     = threadIdx.x;
    const int colbase = wt * 256;     // pot-col base of this tile
    const int rowbase = 4 * sec;

    // stage x tile: 9 rows x 74 float4
    for (int i = tid; i < 9 * 74; i += 256) {
        const int row  = i / 74;
        const int c4   = i % 74;
        const int gcol = colbase + 4 * c4;
        float4 v;
        if (gcol + 3 < WD_) {
            v = *reinterpret_cast<const float4*>(
                x + (size_t)(tt * H_ + rowbase + row) * WD_ + gcol);
        } else {
            v.x = v.y = v.z = v.w = 0.f;
        }
        *reinterpret_cast<float4*>(&lx[row * XT + 4 * c4]) = v;
    }
    __syncthreads();

    const int wpl = tid & 63;    // pooled col within tile (wave-contiguous)
    const int fl  = tid >> 6;    // fm within group (wave-uniform!)
    const int fm0 = fmg * 4;
    const int fm  = fm0 + fl;

    // force scalar (SGPR) weight address: fm is uniform across the wave
    int fm_u = __builtin_amdgcn_readfirstlane(fm);
    fm_u = fm_u < FM ? fm_u : FM - 1;   // clamp OOB fm (50,51); discarded at store
    const float* __restrict__ wsec = Wg + (size_t)(sec * FM + fm_u) * 240;

    float acc[4][4];             // [pot row j][pot col wi]
#pragma unroll
    for (int j = 0; j < 4; ++j)
#pragma unroll
        for (int wi = 0; wi < 4; ++wi) acc[j][wi] = 0.f;

    const float* xbase = &lx[4 * wpl];

#pragma unroll
    for (int a = 0; a < 9; ++a) {     // x row within section (compile-time)
        const int jlo = (a - 5 > 0) ? a - 5 : 0;   // folds to consts per a
        const int jhi = (a < 3) ? a : 3;
        const float* xr = xbase + a * XT;

        float xw[8];
        {
            float4 c0 = *reinterpret_cast<const float4*>(xr);
            xw[0] = c0.x; xw[1] = c0.y; xw[2] = c0.z; xw[3] = c0.w;
        }
#pragma unroll 2
        for (int cq = 0; cq < 10; ++cq) {          // kernel cols, chunks of 4
            float4 nx = *reinterpret_cast<const float4*>(xr + 4 * cq + 4);
            xw[4] = nx.x; xw[5] = nx.y; xw[6] = nx.z; xw[7] = nx.w;
#pragma unroll
            for (int j = jlo; j <= jhi; ++j) {     // pot row; weight row r=a-j
                const float* wr = wsec + (a - j) * 40 + 4 * cq;  // scalar addr
                const float w0 = wr[0], w1 = wr[1], w2 = wr[2], w3 = wr[3];
#pragma unroll
                for (int wi = 0; wi < 4; ++wi) {
                    acc[j][wi] = fmaf(xw[0 + wi], w0, acc[j][wi]);
                    acc[j][wi] = fmaf(xw[1 + wi], w1, acc[j][wi]);
                    acc[j][wi] = fmaf(xw[2 + wi], w2, acc[j][wi]);
                    acc[j][wi] = fmaf(xw[3 + wi], w3, acc[j][wi]);
                }
            }
            xw[0] = xw[4]; xw[1] = xw[5]; xw[2] = xw[6]; xw[3] = xw[7];
        }
    }

    bool any = false;
#pragma unroll
    for (int j = 0; j < 4; ++j)
#pragma unroll
        for (int wi = 0; wi < 4; ++wi) any = any || (acc[j][wi] > THRESH);

    const int wp_real = wt * 64 + wpl;
    if (wp_real < WP && fm < FM) {
        out[((size_t)(sec * T_ + tt) * FM + fm) * WP + wp_real] = any ? 1.0f : 0.0f;
    }
}

// ---------------- Kernel B: init workspace ----------------
__global__ void init_kernel(int* __restrict__ ws)
{
    if (threadIdx.x < NSEC) ws[threadIdx.x] = 0x7fffffff;
}

// ---------------- Kernel C: first-spike scan + argmin reduce ----------------
// grid: 9 sections * 99 blocks (blocks never cross a section)
__global__ __launch_bounds__(256) void scan_kernel(
    const float* __restrict__ pooled, int* __restrict__ ws)
{
    __shared__ int sk[256];
    const int sec = blockIdx.x / 99;
    const int bi  = blockIdx.x % 99;
    const int e   = bi * 256 + threadIdx.x;   // flat (fm*WP + wp) within section
    int key = 0x7fffffff;
    if (e < FM * WP) {
        const int fm = e / WP;
        const int wp = e % WP;
        const size_t base = ((size_t)(sec * T_) * FM + fm) * WP + wp;
        const size_t tstride = (size_t)FM * WP;
#pragma unroll 1
        for (int t = 0; t < T_; ++t) {
            if (pooled[base + t * tstride] > 0.f) { key = (t << 15) | e; break; }
        }
    }
    sk[threadIdx.x] = key;
    __syncthreads();
    for (int s = 128; s > 0; s >>= 1) {
        if (threadIdx.x < s) sk[threadIdx.x] = min(sk[threadIdx.x], sk[threadIdx.x + s]);
        __syncthreads();
    }
    if (threadIdx.x == 0) atomicMin(&ws[sec], sk[0]);
}

// ---------------- Kernel D: finalize winners ----------------
__global__ void finalize_kernel(const int* __restrict__ ws, float* __restrict__ out)
{
    const int i = threadIdx.x;
    if (i < NSEC) {
        const int key = ws[i];
        float feat;
        if (key == 0x7fffffff) feat = -1.0f;
        else                   feat = (float)((key & 32767) / WP);
        out[POOLED_SIZE + i] = feat;
    }
}

extern "C" void kernel_launch(void* const* d_in, const int* in_sizes, int n_in,
                              void* d_out, int out_size, void* d_ws, size_t ws_size,
                              hipStream_t stream) {
    const float* x  = (const float*)d_in[0];
    const float* Wg = (const float*)d_in[1];
    float* out = (float*)d_out;
    int*   ws  = (int*)d_ws;

    hipLaunchKernelGGL(init_kernel, dim3(1), dim3(64), 0, stream, ws);
    hipLaunchKernelGGL(conv_pool_kernel, dim3(28080), dim3(256), 0, stream, x, Wg, out);
    hipLaunchKernelGGL(scan_kernel, dim3(NSEC * 99), dim3(256), 0, stream, out, ws);
    hipLaunchKernelGGL(finalize_kernel, dim3(1), dim3(16), 0, stream, ws, out);
}